// Round 1
// baseline (3546.186 us; speedup 1.0000x reference)
//
#include <hip/hip_runtime.h>
#include <math.h>

#define LRELU_SLOPE 0.2f

// float atomic max via integer bit ordering trick.
// init pattern 0xFFFFFFFF acts as "below everything" in this ordering.
__device__ __forceinline__ void atomicMaxFloatBits(int* addr, float v) {
  int vi = __float_as_int(v);
  if (vi >= 0) atomicMax(addr, vi);
  else atomicMin((unsigned int*)addr, (unsigned int)vi);
}

// Y[n,OUT] = X[n,K] @ W[K,OUT] + bias. 8 rows per block, OUT threads.
template<int K, int OUT>
__global__ void gemm_rows(const float* __restrict__ X, const float* __restrict__ W,
                          const float* __restrict__ bias, float* __restrict__ Y, int n) {
  __shared__ float xs[8][K];
  const int row0 = blockIdx.x * 8;
  const int tid = threadIdx.x;
  for (int i = tid; i < 8 * K; i += OUT) {
    int r = i / K, k = i - r * K;
    int row = row0 + r;
    xs[r][k] = (row < n) ? X[(size_t)row * K + k] : 0.f;
  }
  __syncthreads();
  float acc[8];
#pragma unroll
  for (int r = 0; r < 8; ++r) acc[r] = 0.f;
  for (int k = 0; k < K; ++k) {
    float w = W[(size_t)k * OUT + tid];
#pragma unroll
    for (int r = 0; r < 8; ++r) acc[r] = fmaf(xs[r][k], w, acc[r]);
  }
  float bv = bias[tid];
#pragma unroll
  for (int r = 0; r < 8; ++r) {
    int row = row0 + r;
    if (row < n) Y[(size_t)row * OUT + tid] = acc[r] + bv;
  }
}

// wave per (edge, head); lane = channel (C=64).
template<int Hh>
__global__ void edge_score(const float* __restrict__ xl, const float* __restrict__ xr,
                           const float* __restrict__ att,
                           const int* __restrict__ src, const int* __restrict__ dst,
                           float* __restrict__ score, int* __restrict__ smax, int Ee) {
  const int OUT = Hh * 64;
  int wid = (blockIdx.x * blockDim.x + threadIdx.x) >> 6;
  int lane = threadIdx.x & 63;
  if (wid >= Ee * Hh) return;
  int e = wid / Hh, h = wid - e * Hh;
  int s = src[e], d = dst[e];
  float v = xl[(size_t)s * OUT + h * 64 + lane] + xr[(size_t)d * OUT + h * 64 + lane];
  v = (v > 0.f) ? v : v * LRELU_SLOPE;
  v *= att[h * 64 + lane];
#pragma unroll
  for (int off = 32; off; off >>= 1) v += __shfl_down(v, off);
  if (lane == 0) {
    score[(size_t)e * Hh + h] = v;
    atomicMaxFloatBits(&smax[d * Hh + h], v);
  }
}

template<int Hh>
__global__ void edge_exp(const int* __restrict__ dst, float* __restrict__ score,
                         const int* __restrict__ smax, float* __restrict__ denom, int Ee) {
  int i = blockIdx.x * blockDim.x + threadIdx.x;
  if (i >= Ee * Hh) return;
  int e = i / Hh, h = i - e * Hh;
  int d = dst[e];
  float m = __int_as_float(smax[d * Hh + h]);
  float ex = __expf(score[i] - m);
  score[i] = ex;
  atomicAdd(&denom[d * Hh + h], ex);
}

template<int Hh>
__global__ void edge_scatter(const float* __restrict__ xl, const float* __restrict__ score,
                             const float* __restrict__ denom,
                             const int* __restrict__ src, const int* __restrict__ dst,
                             float* __restrict__ acc, int Ee) {
  const int OUT = Hh * 64;
  int wid = (blockIdx.x * blockDim.x + threadIdx.x) >> 6;
  int lane = threadIdx.x & 63;
  if (wid >= Ee * Hh) return;
  int e = wid / Hh, h = wid - e * Hh;
  int s = src[e], d = dst[e];
  float alpha = score[(size_t)e * Hh + h] / (denom[d * Hh + h] + 1e-16f);
  atomicAdd(&acc[(size_t)d * OUT + h * 64 + lane],
            alpha * xl[(size_t)s * OUT + h * 64 + lane]);
}

// in-place: acc[node,:] = LN(acc[node,:] + bo) * g + b. D threads per block.
template<int D>
__global__ void bias_ln(float* __restrict__ acc, const float* __restrict__ bo,
                        const float* __restrict__ g, const float* __restrict__ bb, int n) {
  __shared__ float red[(D + 63) / 64];
  int node = blockIdx.x;
  int t = threadIdx.x;
  float v = acc[(size_t)node * D + t] + bo[t];
  float s = v;
#pragma unroll
  for (int off = 32; off; off >>= 1) s += __shfl_down(s, off);
  float mu;
  if (D == 64) {
    mu = __shfl(s, 0) * (1.f / D);
  } else {
    if ((t & 63) == 0) red[t >> 6] = s;
    __syncthreads();
    float tot = 0.f;
#pragma unroll
    for (int i = 0; i < D / 64; ++i) tot += red[i];
    mu = tot * (1.f / D);
  }
  float dv = v - mu;
  float s2 = dv * dv;
#pragma unroll
  for (int off = 32; off; off >>= 1) s2 += __shfl_down(s2, off);
  float var;
  if (D == 64) {
    var = __shfl(s2, 0) * (1.f / D);
  } else {
    __syncthreads();
    if ((t & 63) == 0) red[t >> 6] = s2;
    __syncthreads();
    float tot = 0.f;
#pragma unroll
    for (int i = 0; i < D / 64; ++i) tot += red[i];
    var = tot * (1.f / D);
  }
  acc[(size_t)node * D + t] = dv * rsqrtf(var + 1e-5f) * g[t] + bb[t];
}

extern "C" void kernel_launch(void* const* d_in, const int* in_sizes, int n_in,
                              void* d_out, int out_size, void* d_ws, size_t ws_size,
                              hipStream_t stream) {
  const float* x    = (const float*)d_in[0];
  const int*   eidx = (const int*)d_in[1];
  const int Nn = in_sizes[0] / 128;
  const int Ee = in_sizes[1] / 2;
  const int* src = eidx;
  const int* dst = eidx + Ee;

  const float* W1l = (const float*)d_in[3];  const float* b1l = (const float*)d_in[4];
  const float* W1r = (const float*)d_in[5];  const float* b1r = (const float*)d_in[6];
  const float* a1  = (const float*)d_in[7];  const float* bo1 = (const float*)d_in[8];
  const float* g1  = (const float*)d_in[9];  const float* be1 = (const float*)d_in[10];
  const float* W2l = (const float*)d_in[11]; const float* b2l = (const float*)d_in[12];
  const float* W2r = (const float*)d_in[13]; const float* b2r = (const float*)d_in[14];
  const float* a2  = (const float*)d_in[15]; const float* bo2 = (const float*)d_in[16];
  const float* g2  = (const float*)d_in[17]; const float* be2 = (const float*)d_in[18];
  const float* W3l = (const float*)d_in[19]; const float* b3l = (const float*)d_in[20];
  const float* W3r = (const float*)d_in[21]; const float* b3r = (const float*)d_in[22];
  const float* a3  = (const float*)d_in[23]; const float* bo3 = (const float*)d_in[24];
  const float* g3  = (const float*)d_in[25]; const float* be3 = (const float*)d_in[26];
  const float* linW = (const float*)d_in[27]; const float* linb = (const float*)d_in[28];

  char* ws = (char*)d_ws;
  float* xl    = (float*)ws;                ws += (size_t)Nn * 256 * 4;
  float* xr    = (float*)ws;                ws += (size_t)Nn * 256 * 4;
  float* acc   = (float*)ws;                ws += (size_t)Nn * 256 * 4;
  float* score = (float*)ws;                ws += (size_t)Ee * 4 * 4;
  int*   smax  = (int*)ws;                  ws += (size_t)Nn * 4 * 4;
  float* denom = (float*)ws;                ws += (size_t)Nn * 4 * 4;

  const int gemm_blocks = (Nn + 7) / 8;
  const int ewaves4 = Ee * 4;            // (edge, head) waves, H=4
  const int eblocks4 = (ewaves4 + 3) / 4; // 4 waves / 256-thread block
  const int eblocks1 = (Ee + 3) / 4;

  // ---------------- layer 1: 128 -> 4x64 ----------------
  gemm_rows<128, 256><<<gemm_blocks, 256, 0, stream>>>(x, W1l, b1l, xl, Nn);
  gemm_rows<128, 256><<<gemm_blocks, 256, 0, stream>>>(x, W1r, b1r, xr, Nn);
  hipMemsetAsync(smax, 0xFF, (size_t)Nn * 4 * 4, stream);
  hipMemsetAsync(denom, 0, (size_t)Nn * 4 * 4, stream);
  hipMemsetAsync(acc, 0, (size_t)Nn * 256 * 4, stream);
  edge_score<4><<<eblocks4, 256, 0, stream>>>(xl, xr, a1, src, dst, score, smax, Ee);
  edge_exp<4><<<(ewaves4 + 255) / 256, 256, 0, stream>>>(dst, score, smax, denom, Ee);
  edge_scatter<4><<<eblocks4, 256, 0, stream>>>(xl, score, denom, src, dst, acc, Ee);
  bias_ln<256><<<Nn, 256, 0, stream>>>(acc, bo1, g1, be1, Nn);

  // ---------------- layer 2: 256 -> 4x64 ----------------
  gemm_rows<256, 256><<<gemm_blocks, 256, 0, stream>>>(acc, W2l, b2l, xl, Nn);
  gemm_rows<256, 256><<<gemm_blocks, 256, 0, stream>>>(acc, W2r, b2r, xr, Nn);
  hipMemsetAsync(smax, 0xFF, (size_t)Nn * 4 * 4, stream);
  hipMemsetAsync(denom, 0, (size_t)Nn * 4 * 4, stream);
  hipMemsetAsync(acc, 0, (size_t)Nn * 256 * 4, stream);
  edge_score<4><<<eblocks4, 256, 0, stream>>>(xl, xr, a2, src, dst, score, smax, Ee);
  edge_exp<4><<<(ewaves4 + 255) / 256, 256, 0, stream>>>(dst, score, smax, denom, Ee);
  edge_scatter<4><<<eblocks4, 256, 0, stream>>>(xl, score, denom, src, dst, acc, Ee);
  bias_ln<256><<<Nn, 256, 0, stream>>>(acc, bo2, g2, be2, Nn);

  // ---------------- layer 3: 256 -> 1x64 ----------------
  gemm_rows<256, 64><<<gemm_blocks, 64, 0, stream>>>(acc, W3l, b3l, xl, Nn);
  gemm_rows<256, 64><<<gemm_blocks, 64, 0, stream>>>(acc, W3r, b3r, xr, Nn);
  hipMemsetAsync(smax, 0xFF, (size_t)Nn * 1 * 4, stream);
  hipMemsetAsync(denom, 0, (size_t)Nn * 1 * 4, stream);
  hipMemsetAsync(acc, 0, (size_t)Nn * 64 * 4, stream);
  edge_score<1><<<eblocks1, 256, 0, stream>>>(xl, xr, a3, src, dst, score, smax, Ee);
  edge_exp<1><<<(Ee + 255) / 256, 256, 0, stream>>>(dst, score, smax, denom, Ee);
  edge_scatter<1><<<eblocks1, 256, 0, stream>>>(xl, score, denom, src, dst, acc, Ee);
  bias_ln<64><<<Nn, 64, 0, stream>>>(acc, bo3, g3, be3, Nn);

  // ---------------- final linear 64 -> 64 ----------------
  gemm_rows<64, 64><<<gemm_blocks, 64, 0, stream>>>(acc, linW, linb, (float*)d_out, Nn);
}

// Round 2
// 1391.727 us; speedup vs baseline: 2.5480x; 2.5480x over previous
//
#include <hip/hip_runtime.h>
#include <math.h>

#define LRELU_SLOPE 0.2f

// ---------------- GEMM: Y[n,OUT] = X[n,K] @ W[K,OUT] + bias ----------------
template<int K, int OUT>
__global__ void gemm_rows(const float* __restrict__ X, const float* __restrict__ W,
                          const float* __restrict__ bias, float* __restrict__ Y, int n) {
  __shared__ float xs[8][K];
  const int row0 = blockIdx.x * 8;
  const int tid = threadIdx.x;
  for (int i = tid; i < 8 * K; i += OUT) {
    int r = i / K, k = i - r * K;
    int row = row0 + r;
    xs[r][k] = (row < n) ? X[(size_t)row * K + k] : 0.f;
  }
  __syncthreads();
  float acc[8];
#pragma unroll
  for (int r = 0; r < 8; ++r) acc[r] = 0.f;
  for (int k = 0; k < K; ++k) {
    float w = W[(size_t)k * OUT + tid];
#pragma unroll
    for (int r = 0; r < 8; ++r) acc[r] = fmaf(xs[r][k], w, acc[r]);
  }
  float bv = bias[tid];
#pragma unroll
  for (int r = 0; r < 8; ++r) {
    int row = row0 + r;
    if (row < n) Y[(size_t)row * OUT + tid] = acc[r] + bv;
  }
}

// ---------------- CSR build ----------------
__global__ void hist_deg(const int* __restrict__ dst, int* __restrict__ deg, int Ee) {
  int e = blockIdx.x * blockDim.x + threadIdx.x;
  if (e < Ee) atomicAdd(&deg[dst[e]], 1);
}

// one block of 1024 threads; exclusive scan deg[0..n) -> rowptr[0..n]
__global__ void scan_deg(const int* __restrict__ deg, int* __restrict__ rowptr, int n) {
  __shared__ int tot[1024];
  const int t = threadIdx.x;
  const int chunk = (n + 1023) / 1024;
  const int lo = t * chunk;
  const int hi = min(n, lo + chunk);
  int s = 0;
  for (int i = lo; i < hi; ++i) s += deg[i];
  tot[t] = s;
  __syncthreads();
  for (int off = 1; off < 1024; off <<= 1) {
    int v = 0;
    if (t >= off) v = tot[t - off];
    __syncthreads();
    if (t >= off) tot[t] += v;
    __syncthreads();
  }
  int run = (t == 0) ? 0 : tot[t - 1];
  for (int i = lo; i < hi; ++i) { rowptr[i] = run; run += deg[i]; }
  if (t == 1023) rowptr[n] = tot[1023];
}

__global__ void fill_csr(const int* __restrict__ src, const int* __restrict__ dst,
                         const int* __restrict__ rowptr, int* __restrict__ cursor,
                         int* __restrict__ csr_src, int Ee) {
  int e = blockIdx.x * blockDim.x + threadIdx.x;
  if (e >= Ee) return;
  int d = dst[e];
  int p = atomicAdd(&cursor[d], 1);
  csr_src[rowptr[d] + p] = src[e];
}

// ---------------- fused GATv2 aggregation + bias + LayerNorm ----------------
// block = one node, Hh*64 threads; wave = head, lane = channel.
template<int Hh>
__global__ void gat_fused(const float* __restrict__ xl, const float* __restrict__ xr,
                          const float* __restrict__ att,
                          const int* __restrict__ rowptr, const int* __restrict__ csr_src,
                          const float* __restrict__ bo, const float* __restrict__ g,
                          const float* __restrict__ bb,
                          float* __restrict__ out, int n) {
  const int OUT = Hh * 64;
  const int node = blockIdx.x;
  const int t = threadIdx.x;
  const int h = t >> 6;
  (void)h;
  const int r0 = rowptr[node];
  const int r1 = rowptr[node + 1];

  const float xr_d = xr[(size_t)node * OUT + t];
  const float att_v = att[t];

  float m = -INFINITY, s = 0.f, o = 0.f;

  int i = r0;
  int sn = (i < r1) ? csr_src[i] : 0;
  float v = (i < r1) ? xl[(size_t)sn * OUT + t] : 0.f;
  while (i < r1) {
    float vc = v;
    ++i;
    if (i < r1) {
      int sn2 = csr_src[i];
      v = xl[(size_t)sn2 * OUT + t];
    }
    float e = vc + xr_d;
    e = (e > 0.f) ? e : e * LRELU_SLOPE;
    float sc = e * att_v;
#pragma unroll
    for (int off = 1; off < 64; off <<= 1) sc += __shfl_xor(sc, off);
    float nm = fmaxf(m, sc);
    float scale = __expf(m - nm);
    float w = __expf(sc - nm);
    s = s * scale + w;
    o = o * scale + w * vc;
    m = nm;
  }

  float val = o / (s + 1e-16f) + bo[t];

  // LayerNorm over OUT channels within the block
  __shared__ float red[Hh > 1 ? Hh : 1];
  float a1 = val;
#pragma unroll
  for (int off = 1; off < 64; off <<= 1) a1 += __shfl_xor(a1, off);
  float mu;
  if (Hh == 1) {
    mu = a1 * (1.f / OUT);
  } else {
    if ((t & 63) == 0) red[t >> 6] = a1;
    __syncthreads();
    float tot = 0.f;
#pragma unroll
    for (int k = 0; k < Hh; ++k) tot += red[k];
    mu = tot * (1.f / OUT);
  }
  float dv = val - mu;
  float q = dv * dv;
#pragma unroll
  for (int off = 1; off < 64; off <<= 1) q += __shfl_xor(q, off);
  float var;
  if (Hh == 1) {
    var = q * (1.f / OUT);
  } else {
    __syncthreads();
    if ((t & 63) == 0) red[t >> 6] = q;
    __syncthreads();
    float tot = 0.f;
#pragma unroll
    for (int k = 0; k < Hh; ++k) tot += red[k];
    var = tot * (1.f / OUT);
  }
  out[(size_t)node * OUT + t] = dv * rsqrtf(var + 1e-5f) * g[t] + bb[t];
}

extern "C" void kernel_launch(void* const* d_in, const int* in_sizes, int n_in,
                              void* d_out, int out_size, void* d_ws, size_t ws_size,
                              hipStream_t stream) {
  const float* x    = (const float*)d_in[0];
  const int*   eidx = (const int*)d_in[1];
  const int Nn = in_sizes[0] / 128;
  const int Ee = in_sizes[1] / 2;
  const int* src = eidx;
  const int* dst = eidx + Ee;

  const float* W1l = (const float*)d_in[3];  const float* b1l = (const float*)d_in[4];
  const float* W1r = (const float*)d_in[5];  const float* b1r = (const float*)d_in[6];
  const float* a1  = (const float*)d_in[7];  const float* bo1 = (const float*)d_in[8];
  const float* g1  = (const float*)d_in[9];  const float* be1 = (const float*)d_in[10];
  const float* W2l = (const float*)d_in[11]; const float* b2l = (const float*)d_in[12];
  const float* W2r = (const float*)d_in[13]; const float* b2r = (const float*)d_in[14];
  const float* a2  = (const float*)d_in[15]; const float* bo2 = (const float*)d_in[16];
  const float* g2  = (const float*)d_in[17]; const float* be2 = (const float*)d_in[18];
  const float* W3l = (const float*)d_in[19]; const float* b3l = (const float*)d_in[20];
  const float* W3r = (const float*)d_in[21]; const float* b3r = (const float*)d_in[22];
  const float* a3  = (const float*)d_in[23]; const float* bo3 = (const float*)d_in[24];
  const float* g3  = (const float*)d_in[25]; const float* be3 = (const float*)d_in[26];
  const float* linW = (const float*)d_in[27]; const float* linb = (const float*)d_in[28];

  char* ws = (char*)d_ws;
  float* xl     = (float*)ws;  ws += (size_t)Nn * 256 * 4;
  float* xr     = (float*)ws;  ws += (size_t)Nn * 256 * 4;
  float* h      = (float*)ws;  ws += (size_t)Nn * 256 * 4;
  int*   deg    = (int*)ws;    ws += (size_t)Nn * 4;
  int*   cursor = (int*)ws;    ws += (size_t)Nn * 4;
  int*   rowptr = (int*)ws;    ws += (size_t)(Nn + 1) * 4;
  int*   csr_src= (int*)ws;    ws += (size_t)Ee * 4;

  const int gemm_blocks = (Nn + 7) / 8;
  const int eblk = (Ee + 255) / 256;

  // ---------------- CSR build (by dst) ----------------
  hipMemsetAsync(deg, 0, (size_t)Nn * 4, stream);
  hipMemsetAsync(cursor, 0, (size_t)Nn * 4, stream);
  hist_deg<<<eblk, 256, 0, stream>>>(dst, deg, Ee);
  scan_deg<<<1, 1024, 0, stream>>>(deg, rowptr, Nn);
  fill_csr<<<eblk, 256, 0, stream>>>(src, dst, rowptr, cursor, csr_src, Ee);

  // ---------------- layer 1: 128 -> 4x64 ----------------
  gemm_rows<128, 256><<<gemm_blocks, 256, 0, stream>>>(x, W1l, b1l, xl, Nn);
  gemm_rows<128, 256><<<gemm_blocks, 256, 0, stream>>>(x, W1r, b1r, xr, Nn);
  gat_fused<4><<<Nn, 256, 0, stream>>>(xl, xr, a1, rowptr, csr_src, bo1, g1, be1, h, Nn);

  // ---------------- layer 2: 256 -> 4x64 ----------------
  gemm_rows<256, 256><<<gemm_blocks, 256, 0, stream>>>(h, W2l, b2l, xl, Nn);
  gemm_rows<256, 256><<<gemm_blocks, 256, 0, stream>>>(h, W2r, b2r, xr, Nn);
  gat_fused<4><<<Nn, 256, 0, stream>>>(xl, xr, a2, rowptr, csr_src, bo2, g2, be2, h, Nn);

  // ---------------- layer 3: 256 -> 1x64 ----------------
  gemm_rows<256, 64><<<gemm_blocks, 64, 0, stream>>>(h, W3l, b3l, xl, Nn);
  gemm_rows<256, 64><<<gemm_blocks, 64, 0, stream>>>(h, W3r, b3r, xr, Nn);
  gat_fused<1><<<Nn, 64, 0, stream>>>(xl, xr, a3, rowptr, csr_src, bo3, g3, be3, h, Nn);

  // ---------------- final linear 64 -> 64 ----------------
  gemm_rows<64, 64><<<gemm_blocks, 64, 0, stream>>>(h, linW, linb, (float*)d_out, Nn);
}

// Round 3
// 1042.952 us; speedup vs baseline: 3.4001x; 1.3344x over previous
//
#include <hip/hip_runtime.h>
#include <math.h>

#define LRELU_SLOPE 0.2f

// ---------------- GEMM: Y[n,OUT] = X[n,K] @ W[K,OUT] + bias ----------------
// 256 threads; NG = 256/OUT column-groups; ROWS rows per block.
template<int K, int OUT, int ROWS>
__global__ __launch_bounds__(256) void gemm_rows(const float* __restrict__ X,
    const float* __restrict__ W, const float* __restrict__ bias,
    float* __restrict__ Y, int n) {
  __shared__ float xs[ROWS][K];
  constexpr int NG = 256 / OUT;
  constexpr int RPG = ROWS / NG;
  const int row0 = blockIdx.x * ROWS;
  const int tid = threadIdx.x;
  const int col = tid % OUT;
  const int rg  = tid / OUT;
  for (int i = tid; i < ROWS * K; i += 256) {
    int r = i / K, k = i - r * K;
    int row = row0 + r;
    xs[r][k] = (row < n) ? X[(size_t)row * K + k] : 0.f;
  }
  __syncthreads();
  float acc[RPG];
#pragma unroll
  for (int r = 0; r < RPG; ++r) acc[r] = 0.f;
  for (int k = 0; k < K; ++k) {
    float w = W[(size_t)k * OUT + col];
#pragma unroll
    for (int r = 0; r < RPG; ++r) acc[r] = fmaf(xs[rg * RPG + r][k], w, acc[r]);
  }
  float bv = bias[col];
#pragma unroll
  for (int r = 0; r < RPG; ++r) {
    int row = row0 + rg * RPG + r;
    if (row < n) Y[(size_t)row * OUT + col] = acc[r] + bv;
  }
}

// ---------------- CSR build ----------------
__global__ void hist_deg(const int* __restrict__ dst, int* __restrict__ deg, int Ee) {
  int e = blockIdx.x * blockDim.x + threadIdx.x;
  if (e < Ee) atomicAdd(&deg[dst[e]], 1);
}

__global__ void scan_deg(const int* __restrict__ deg, int* __restrict__ rowptr, int n) {
  __shared__ int tot[1024];
  const int t = threadIdx.x;
  const int chunk = (n + 1023) / 1024;
  const int lo = t * chunk;
  const int hi = min(n, lo + chunk);
  int s = 0;
  for (int i = lo; i < hi; ++i) s += deg[i];
  tot[t] = s;
  __syncthreads();
  for (int off = 1; off < 1024; off <<= 1) {
    int v = 0;
    if (t >= off) v = tot[t - off];
    __syncthreads();
    if (t >= off) tot[t] += v;
    __syncthreads();
  }
  int run = (t == 0) ? 0 : tot[t - 1];
  for (int i = lo; i < hi; ++i) { rowptr[i] = run; run += deg[i]; }
  if (t == 1023) rowptr[n] = tot[1023];
}

__global__ void fill_csr(const int* __restrict__ src, const int* __restrict__ dst,
                         const int* __restrict__ rowptr, int* __restrict__ cursor,
                         int* __restrict__ csr_src, int Ee) {
  int e = blockIdx.x * blockDim.x + threadIdx.x;
  if (e >= Ee) return;
  int d = dst[e];
  int p = atomicAdd(&cursor[d], 1);
  csr_src[rowptr[d] + p] = src[e];
}

// ---------------- fused GATv2 aggregation + bias + LayerNorm ----------------
// 256 threads = 4 waves. Hh==4: block = node, wave = head.
// Hh==1: block = 4 nodes, wave = node.
// Within a wave: 4 groups of 16 lanes, group g handles edge base+g; each lane
// holds 4 channels (float4). 4 edges per iteration.
template<int Hh>
__global__ __launch_bounds__(256) void gat_fused(
    const float* __restrict__ xl, const float* __restrict__ xr,
    const float* __restrict__ att,
    const int* __restrict__ rowptr, const int* __restrict__ csr_src,
    const float* __restrict__ bo, const float* __restrict__ gam,
    const float* __restrict__ bet, float* __restrict__ out, int n) {
  const int OUT = Hh * 64;
  const int t = threadIdx.x;
  const int wv = t >> 6, lane = t & 63;
  const int grp = lane >> 4, c4 = lane & 15;
  __shared__ float red[4];
  int node, h;
  if (Hh == 4) { node = blockIdx.x; h = wv; }
  else         { node = blockIdx.x * 4 + wv; h = 0; }
  const bool active = node < n;
  const int cb = h * 64 + c4 * 4;

  float4 xr4 = {0.f, 0.f, 0.f, 0.f};
  float4 v   = {0.f, 0.f, 0.f, 0.f};
  int r0 = 0, r1 = 0;
  if (active) {
    xr4 = *(const float4*)(xr + (size_t)node * OUT + cb);
    r0 = rowptr[node];
    r1 = rowptr[node + 1];
  }
  const float4 at4 = *(const float4*)(att + cb);

  float m = -INFINITY, s = 0.f;
  float4 o = {0.f, 0.f, 0.f, 0.f};

  {
    int i0 = r0 + grp;
    if (i0 < r1) {
      int sn = csr_src[i0];
      v = *(const float4*)(xl + (size_t)sn * OUT + cb);
    }
  }
  bool valid = (r0 + grp) < r1;

  for (int base = r0; base < r1; base += 4) {
    const float4 vc = v;
    const bool vld = valid;
    int inext = base + 4 + grp;
    valid = inext < r1;
    if (valid) {
      int sn = csr_src[inext];
      v = *(const float4*)(xl + (size_t)sn * OUT + cb);
    }
    float e0 = vc.x + xr4.x; e0 = (e0 > 0.f) ? e0 : e0 * LRELU_SLOPE;
    float e1 = vc.y + xr4.y; e1 = (e1 > 0.f) ? e1 : e1 * LRELU_SLOPE;
    float e2 = vc.z + xr4.z; e2 = (e2 > 0.f) ? e2 : e2 * LRELU_SLOPE;
    float e3 = vc.w + xr4.w; e3 = (e3 > 0.f) ? e3 : e3 * LRELU_SLOPE;
    float sc = fmaf(e3, at4.w, fmaf(e2, at4.z, fmaf(e1, at4.y, e0 * at4.x)));
    sc += __shfl_xor(sc, 1);
    sc += __shfl_xor(sc, 2);
    sc += __shfl_xor(sc, 4);
    sc += __shfl_xor(sc, 8);
    if (!vld) sc = -INFINITY;
    const float s0 = __shfl(sc, 0),  s1 = __shfl(sc, 16);
    const float s2 = __shfl(sc, 32), s3 = __shfl(sc, 48);
    const float nm = fmaxf(m, fmaxf(fmaxf(s0, s1), fmaxf(s2, s3)));
    const float scale = __expf(m - nm);
    const float wsum = __expf(s0 - nm) + __expf(s1 - nm) +
                       __expf(s2 - nm) + __expf(s3 - nm);
    const float wown = __expf(sc - nm);
    s = fmaf(s, scale, wsum);
    o.x = fmaf(o.x, scale, wown * vc.x);
    o.y = fmaf(o.y, scale, wown * vc.y);
    o.z = fmaf(o.z, scale, wown * vc.z);
    o.w = fmaf(o.w, scale, wown * vc.w);
    m = nm;
  }

  // sum partial accumulators across the 4 edge-groups
  o.x += __shfl_xor(o.x, 16); o.y += __shfl_xor(o.y, 16);
  o.z += __shfl_xor(o.z, 16); o.w += __shfl_xor(o.w, 16);
  o.x += __shfl_xor(o.x, 32); o.y += __shfl_xor(o.y, 32);
  o.z += __shfl_xor(o.z, 32); o.w += __shfl_xor(o.w, 32);

  const float inv = 1.f / (s + 1e-16f);
  const float4 bo4 = *(const float4*)(bo + cb);
  const float v0 = fmaf(o.x, inv, bo4.x);
  const float v1 = fmaf(o.y, inv, bo4.y);
  const float v2 = fmaf(o.z, inv, bo4.z);
  const float v3 = fmaf(o.w, inv, bo4.w);

  // ---- LayerNorm over OUT channels (each group replicates the head 4x) ----
  float ls = v0 + v1 + v2 + v3;
#pragma unroll
  for (int off = 1; off < 64; off <<= 1) ls += __shfl_xor(ls, off);
  float mu;
  if (Hh == 4) {
    if (lane == 0) red[wv] = ls;
    __syncthreads();
    mu = (red[0] + red[1] + red[2] + red[3]) * (0.25f / 256.f);
  } else {
    mu = ls * (0.25f / 64.f);
  }
  const float d0 = v0 - mu, d1 = v1 - mu, d2 = v2 - mu, d3 = v3 - mu;
  float q = d0 * d0 + d1 * d1 + d2 * d2 + d3 * d3;
#pragma unroll
  for (int off = 1; off < 64; off <<= 1) q += __shfl_xor(q, off);
  float var;
  if (Hh == 4) {
    __syncthreads();
    if (lane == 0) red[wv] = q;
    __syncthreads();
    var = (red[0] + red[1] + red[2] + red[3]) * (0.25f / 256.f);
  } else {
    var = q * (0.25f / 64.f);
  }
  const float rs = rsqrtf(var + 1e-5f);

  if (active && grp == 0) {
    const float4 g4 = *(const float4*)(gam + cb);
    const float4 b4 = *(const float4*)(bet + cb);
    float4 res;
    res.x = fmaf(d0 * rs, g4.x, b4.x);
    res.y = fmaf(d1 * rs, g4.y, b4.y);
    res.z = fmaf(d2 * rs, g4.z, b4.z);
    res.w = fmaf(d3 * rs, g4.w, b4.w);
    *(float4*)(out + (size_t)node * OUT + cb) = res;
  }
}

extern "C" void kernel_launch(void* const* d_in, const int* in_sizes, int n_in,
                              void* d_out, int out_size, void* d_ws, size_t ws_size,
                              hipStream_t stream) {
  const float* x    = (const float*)d_in[0];
  const int*   eidx = (const int*)d_in[1];
  const int Nn = in_sizes[0] / 128;
  const int Ee = in_sizes[1] / 2;
  const int* src = eidx;
  const int* dst = eidx + Ee;

  const float* W1l = (const float*)d_in[3];  const float* b1l = (const float*)d_in[4];
  const float* W1r = (const float*)d_in[5];  const float* b1r = (const float*)d_in[6];
  const float* a1  = (const float*)d_in[7];  const float* bo1 = (const float*)d_in[8];
  const float* g1  = (const float*)d_in[9];  const float* be1 = (const float*)d_in[10];
  const float* W2l = (const float*)d_in[11]; const float* b2l = (const float*)d_in[12];
  const float* W2r = (const float*)d_in[13]; const float* b2r = (const float*)d_in[14];
  const float* a2  = (const float*)d_in[15]; const float* bo2 = (const float*)d_in[16];
  const float* g2  = (const float*)d_in[17]; const float* be2 = (const float*)d_in[18];
  const float* W3l = (const float*)d_in[19]; const float* b3l = (const float*)d_in[20];
  const float* W3r = (const float*)d_in[21]; const float* b3r = (const float*)d_in[22];
  const float* a3  = (const float*)d_in[23]; const float* bo3 = (const float*)d_in[24];
  const float* g3  = (const float*)d_in[25]; const float* be3 = (const float*)d_in[26];
  const float* linW = (const float*)d_in[27]; const float* linb = (const float*)d_in[28];

  char* ws = (char*)d_ws;
  float* xl     = (float*)ws;  ws += (size_t)Nn * 256 * 4;
  float* xr     = (float*)ws;  ws += (size_t)Nn * 256 * 4;
  float* h      = (float*)ws;  ws += (size_t)Nn * 256 * 4;
  int*   deg    = (int*)ws;    ws += (size_t)Nn * 4;
  int*   cursor = (int*)ws;    ws += (size_t)Nn * 4;
  int*   rowptr = (int*)ws;    ws += (size_t)(Nn + 1) * 4;
  int*   csr_src= (int*)ws;    ws += (size_t)Ee * 4;

  const int gemm_blocks = (Nn + 15) / 16;
  const int eblk = (Ee + 255) / 256;

  // ---------------- CSR build (by dst) ----------------
  hipMemsetAsync(deg, 0, (size_t)Nn * 4, stream);
  hipMemsetAsync(cursor, 0, (size_t)Nn * 4, stream);
  hist_deg<<<eblk, 256, 0, stream>>>(dst, deg, Ee);
  scan_deg<<<1, 1024, 0, stream>>>(deg, rowptr, Nn);
  fill_csr<<<eblk, 256, 0, stream>>>(src, dst, rowptr, cursor, csr_src, Ee);

  // ---------------- layer 1: 128 -> 4x64 ----------------
  gemm_rows<128, 256, 16><<<gemm_blocks, 256, 0, stream>>>(x, W1l, b1l, xl, Nn);
  gemm_rows<128, 256, 16><<<gemm_blocks, 256, 0, stream>>>(x, W1r, b1r, xr, Nn);
  gat_fused<4><<<Nn, 256, 0, stream>>>(xl, xr, a1, rowptr, csr_src, bo1, g1, be1, h, Nn);

  // ---------------- layer 2: 256 -> 4x64 ----------------
  gemm_rows<256, 256, 16><<<gemm_blocks, 256, 0, stream>>>(h, W2l, b2l, xl, Nn);
  gemm_rows<256, 256, 16><<<gemm_blocks, 256, 0, stream>>>(h, W2r, b2r, xr, Nn);
  gat_fused<4><<<Nn, 256, 0, stream>>>(xl, xr, a2, rowptr, csr_src, bo2, g2, be2, h, Nn);

  // ---------------- layer 3: 256 -> 1x64 ----------------
  gemm_rows<256, 64, 16><<<gemm_blocks, 256, 0, stream>>>(h, W3l, b3l, xl, Nn);
  gemm_rows<256, 64, 16><<<gemm_blocks, 256, 0, stream>>>(h, W3r, b3r, xr, Nn);
  gat_fused<1><<<(Nn + 3) / 4, 256, 0, stream>>>(xl, xr, a3, rowptr, csr_src, bo3, g3, be3, h, Nn);

  // ---------------- final linear 64 -> 64 ----------------
  gemm_rows<64, 64, 16><<<gemm_blocks, 256, 0, stream>>>(h, linW, linb, (float*)d_out, Nn);
}

// Round 4
// 799.203 us; speedup vs baseline: 4.4372x; 1.3050x over previous
//
#include <hip/hip_runtime.h>
#include <math.h>

#define LRELU_SLOPE 0.2f

typedef __attribute__((ext_vector_type(8))) short bf16x8;
typedef __attribute__((ext_vector_type(4))) float f32x4;

// ---------------- f32 -> bf16 (RNE) ----------------
__device__ __forceinline__ unsigned short f2bf(float f) {
  unsigned u = __float_as_uint(f);
  return (unsigned short)((u + 0x7FFFu + ((u >> 16) & 1u)) >> 16);
}

__global__ void cvt_bf16(const float* __restrict__ in, unsigned short* __restrict__ out, int n4) {
  int i = blockIdx.x * blockDim.x + threadIdx.x;
  if (i >= n4) return;
  float4 v = *(const float4*)(in + (size_t)i * 4);
  ushort4 o;
  o.x = f2bf(v.x); o.y = f2bf(v.y); o.z = f2bf(v.z); o.w = f2bf(v.w);
  *(ushort4*)(out + (size_t)i * 4) = o;
}

// W[K][N] f32 -> Wt[N][K] bf16
__global__ void wt_cvt(const float* __restrict__ W, unsigned short* __restrict__ Wt, int K, int N) {
  int i = blockIdx.x * blockDim.x + threadIdx.x;
  int k8s = K / 8;
  int n = i / k8s, k8 = i - n * k8s;
  if (n >= N) return;
  unsigned short tmp[8];
#pragma unroll
  for (int j = 0; j < 8; ++j) tmp[j] = f2bf(W[(size_t)(k8 * 8 + j) * N + n]);
  *(bf16x8*)(Wt + (size_t)n * K + k8 * 8) = *(bf16x8*)tmp;
}

// ---------------- MFMA GEMM: Y[M][N] = Xb[M][K](bf16) @ Wt[N][K](bf16)^T + bias ----------------
// block: 256 thr = 4 waves; wave w: rows [rowBase + w*RT*16, +RT*16); cols: 64 per blockIdx.y
template<int K, int RT>
__global__ __launch_bounds__(256) void gemm_mfma(
    const unsigned short* __restrict__ Xb, const unsigned short* __restrict__ Wt,
    const float* __restrict__ bias, float* __restrict__ Y, int M, int N) {
  const int t = threadIdx.x, w = t >> 6, l = t & 63;
  const int lr = l & 15, lk = l >> 4;
  const int n0 = blockIdx.y * 64;
  const int rowBase = blockIdx.x * (RT * 64) + w * (RT * 16);

  f32x4 acc[RT][4];
#pragma unroll
  for (int rt = 0; rt < RT; ++rt)
#pragma unroll
    for (int nt = 0; nt < 4; ++nt) acc[rt][nt] = (f32x4){0.f, 0.f, 0.f, 0.f};

  const unsigned short* ap[RT];
#pragma unroll
  for (int rt = 0; rt < RT; ++rt) {
    int row = rowBase + rt * 16 + lr;
    if (row >= M) row = M - 1;
    ap[rt] = Xb + (size_t)row * K + lk * 8;
  }
  const unsigned short* bp = Wt + (size_t)(n0 + lr) * K + lk * 8;

#pragma unroll
  for (int k0 = 0; k0 < K; k0 += 32) {
    bf16x8 a[RT], b[4];
#pragma unroll
    for (int rt = 0; rt < RT; ++rt) a[rt] = *(const bf16x8*)(ap[rt] + k0);
#pragma unroll
    for (int nt = 0; nt < 4; ++nt) b[nt] = *(const bf16x8*)(bp + (size_t)nt * 16 * K + k0);
#pragma unroll
    for (int rt = 0; rt < RT; ++rt)
#pragma unroll
      for (int nt = 0; nt < 4; ++nt)
        acc[rt][nt] = __builtin_amdgcn_mfma_f32_16x16x32_bf16(a[rt], b[nt], acc[rt][nt], 0, 0, 0);
  }

#pragma unroll
  for (int nt = 0; nt < 4; ++nt) {
    float bv = bias[n0 + nt * 16 + lr];
#pragma unroll
    for (int rt = 0; rt < RT; ++rt) {
#pragma unroll
      for (int r = 0; r < 4; ++r) {
        int row = rowBase + rt * 16 + lk * 4 + r;
        if (row < M) Y[(size_t)row * N + n0 + nt * 16 + lr] = acc[rt][nt][r] + bv;
      }
    }
  }
}

// ---------------- f32 GEMM (final linear) ----------------
template<int K, int OUT, int ROWS>
__global__ __launch_bounds__(256) void gemm_rows(const float* __restrict__ X,
    const float* __restrict__ W, const float* __restrict__ bias,
    float* __restrict__ Y, int n) {
  __shared__ float xs[ROWS][K];
  constexpr int NG = 256 / OUT;
  constexpr int RPG = ROWS / NG;
  const int row0 = blockIdx.x * ROWS;
  const int tid = threadIdx.x;
  const int col = tid % OUT;
  const int rg  = tid / OUT;
  for (int i = tid; i < ROWS * K; i += 256) {
    int r = i / K, k = i - r * K;
    int row = row0 + r;
    xs[r][k] = (row < n) ? X[(size_t)row * K + k] : 0.f;
  }
  __syncthreads();
  float acc[RPG];
#pragma unroll
  for (int r = 0; r < RPG; ++r) acc[r] = 0.f;
  for (int k = 0; k < K; ++k) {
    float w = W[(size_t)k * OUT + col];
#pragma unroll
    for (int r = 0; r < RPG; ++r) acc[r] = fmaf(xs[rg * RPG + r][k], w, acc[r]);
  }
  float bv = bias[col];
#pragma unroll
  for (int r = 0; r < RPG; ++r) {
    int row = row0 + rg * RPG + r;
    if (row < n) Y[(size_t)row * OUT + col] = acc[r] + bv;
  }
}

// ---------------- CSR build ----------------
__global__ void hist_deg(const int* __restrict__ dst, int* __restrict__ deg, int Ee) {
  int e = blockIdx.x * blockDim.x + threadIdx.x;
  if (e < Ee) atomicAdd(&deg[dst[e]], 1);
}

__global__ void scan_deg(const int* __restrict__ deg, int* __restrict__ rowptr, int n) {
  __shared__ int tot[1024];
  const int t = threadIdx.x;
  const int chunk = (n + 1023) / 1024;
  const int lo = t * chunk;
  const int hi = min(n, lo + chunk);
  int s = 0;
  for (int i = lo; i < hi; ++i) s += deg[i];
  tot[t] = s;
  __syncthreads();
  for (int off = 1; off < 1024; off <<= 1) {
    int v = 0;
    if (t >= off) v = tot[t - off];
    __syncthreads();
    if (t >= off) tot[t] += v;
    __syncthreads();
  }
  int run = (t == 0) ? 0 : tot[t - 1];
  for (int i = lo; i < hi; ++i) { rowptr[i] = run; run += deg[i]; }
  if (t == 1023) rowptr[n] = tot[1023];
}

__global__ void fill_csr(const int* __restrict__ src, const int* __restrict__ dst,
                         const int* __restrict__ rowptr, int* __restrict__ cursor,
                         int* __restrict__ csr_src, int Ee) {
  int e = blockIdx.x * blockDim.x + threadIdx.x;
  if (e >= Ee) return;
  int d = dst[e];
  int p = atomicAdd(&cursor[d], 1);
  csr_src[rowptr[d] + p] = src[e];
}

// ---------------- fused GATv2 aggregation + bias + LayerNorm ----------------
template<int Hh>
__global__ __launch_bounds__(256) void gat_fused(
    const float* __restrict__ xl, const float* __restrict__ xr,
    const float* __restrict__ att,
    const int* __restrict__ rowptr, const int* __restrict__ csr_src,
    const float* __restrict__ bo, const float* __restrict__ gam,
    const float* __restrict__ bet, float* __restrict__ out, int n) {
  const int OUT = Hh * 64;
  const int t = threadIdx.x;
  const int wv = t >> 6, lane = t & 63;
  const int grp = lane >> 4, c4 = lane & 15;
  __shared__ float red[4];
  int node, h;
  if (Hh == 4) { node = blockIdx.x; h = wv; }
  else         { node = blockIdx.x * 4 + wv; h = 0; }
  const bool active = node < n;
  const int cb = h * 64 + c4 * 4;

  float4 xr4 = {0.f, 0.f, 0.f, 0.f};
  float4 v   = {0.f, 0.f, 0.f, 0.f};
  int r0 = 0, r1 = 0;
  if (active) {
    xr4 = *(const float4*)(xr + (size_t)node * OUT + cb);
    r0 = rowptr[node];
    r1 = rowptr[node + 1];
  }
  const float4 at4 = *(const float4*)(att + cb);

  float m = -INFINITY, s = 0.f;
  float4 o = {0.f, 0.f, 0.f, 0.f};

  {
    int i0 = r0 + grp;
    if (i0 < r1) {
      int sn = csr_src[i0];
      v = *(const float4*)(xl + (size_t)sn * OUT + cb);
    }
  }
  bool valid = (r0 + grp) < r1;

  for (int base = r0; base < r1; base += 4) {
    const float4 vc = v;
    const bool vld = valid;
    int inext = base + 4 + grp;
    valid = inext < r1;
    if (valid) {
      int sn = csr_src[inext];
      v = *(const float4*)(xl + (size_t)sn * OUT + cb);
    }
    float e0 = vc.x + xr4.x; e0 = fmaxf(e0, LRELU_SLOPE * e0);
    float e1 = vc.y + xr4.y; e1 = fmaxf(e1, LRELU_SLOPE * e1);
    float e2 = vc.z + xr4.z; e2 = fmaxf(e2, LRELU_SLOPE * e2);
    float e3 = vc.w + xr4.w; e3 = fmaxf(e3, LRELU_SLOPE * e3);
    float sc = fmaf(e3, at4.w, fmaf(e2, at4.z, fmaf(e1, at4.y, e0 * at4.x)));
    sc += __shfl_xor(sc, 1);
    sc += __shfl_xor(sc, 2);
    sc += __shfl_xor(sc, 4);
    sc += __shfl_xor(sc, 8);
    if (!vld) sc = -INFINITY;
    // cross-group max (4 groups of 16)
    float mx = fmaxf(sc, __shfl_xor(sc, 16));
    mx = fmaxf(mx, __shfl_xor(mx, 32));
    const float nm = fmaxf(m, mx);
    const float scale = __expf(m - nm);
    const float wown = __expf(sc - nm);         // 0 for invalid (exp(-inf))
    float ws = wown + __shfl_xor(wown, 16);
    ws += __shfl_xor(ws, 32);
    s = fmaf(s, scale, ws);
    o.x = fmaf(o.x, scale, wown * vc.x);
    o.y = fmaf(o.y, scale, wown * vc.y);
    o.z = fmaf(o.z, scale, wown * vc.z);
    o.w = fmaf(o.w, scale, wown * vc.w);
    m = nm;
  }

  // sum partial accumulators across the 4 edge-groups
  o.x += __shfl_xor(o.x, 16); o.y += __shfl_xor(o.y, 16);
  o.z += __shfl_xor(o.z, 16); o.w += __shfl_xor(o.w, 16);
  o.x += __shfl_xor(o.x, 32); o.y += __shfl_xor(o.y, 32);
  o.z += __shfl_xor(o.z, 32); o.w += __shfl_xor(o.w, 32);

  const float inv = 1.f / (s + 1e-16f);
  const float4 bo4 = *(const float4*)(bo + cb);
  const float v0 = fmaf(o.x, inv, bo4.x);
  const float v1 = fmaf(o.y, inv, bo4.y);
  const float v2 = fmaf(o.z, inv, bo4.z);
  const float v3 = fmaf(o.w, inv, bo4.w);

  // ---- LayerNorm over OUT channels ----
  float ls = v0 + v1 + v2 + v3;
#pragma unroll
  for (int off = 1; off < 64; off <<= 1) ls += __shfl_xor(ls, off);
  float mu;
  if (Hh == 4) {
    if (lane == 0) red[wv] = ls;
    __syncthreads();
    mu = (red[0] + red[1] + red[2] + red[3]) * (0.25f / 256.f);
  } else {
    mu = ls * (0.25f / 64.f);
  }
  const float d0 = v0 - mu, d1 = v1 - mu, d2 = v2 - mu, d3 = v3 - mu;
  float q = d0 * d0 + d1 * d1 + d2 * d2 + d3 * d3;
#pragma unroll
  for (int off = 1; off < 64; off <<= 1) q += __shfl_xor(q, off);
  float var;
  if (Hh == 4) {
    __syncthreads();
    if (lane == 0) red[wv] = q;
    __syncthreads();
    var = (red[0] + red[1] + red[2] + red[3]) * (0.25f / 256.f);
  } else {
    var = q * (0.25f / 64.f);
  }
  const float rs = rsqrtf(var + 1e-5f);

  if (active && grp == 0) {
    const float4 g4 = *(const float4*)(gam + cb);
    const float4 b4 = *(const float4*)(bet + cb);
    float4 res;
    res.x = fmaf(d0 * rs, g4.x, b4.x);
    res.y = fmaf(d1 * rs, g4.y, b4.y);
    res.z = fmaf(d2 * rs, g4.z, b4.z);
    res.w = fmaf(d3 * rs, g4.w, b4.w);
    *(float4*)(out + (size_t)node * OUT + cb) = res;
  }
}

extern "C" void kernel_launch(void* const* d_in, const int* in_sizes, int n_in,
                              void* d_out, int out_size, void* d_ws, size_t ws_size,
                              hipStream_t stream) {
  const float* x    = (const float*)d_in[0];
  const int*   eidx = (const int*)d_in[1];
  const int Nn = in_sizes[0] / 128;
  const int Ee = in_sizes[1] / 2;
  const int* src = eidx;
  const int* dst = eidx + Ee;

  const float* W1l = (const float*)d_in[3];  const float* b1l = (const float*)d_in[4];
  const float* W1r = (const float*)d_in[5];  const float* b1r = (const float*)d_in[6];
  const float* a1  = (const float*)d_in[7];  const float* bo1 = (const float*)d_in[8];
  const float* g1  = (const float*)d_in[9];  const float* be1 = (const float*)d_in[10];
  const float* W2l = (const float*)d_in[11]; const float* b2l = (const float*)d_in[12];
  const float* W2r = (const float*)d_in[13]; const float* b2r = (const float*)d_in[14];
  const float* a2  = (const float*)d_in[15]; const float* bo2 = (const float*)d_in[16];
  const float* g2  = (const float*)d_in[17]; const float* be2 = (const float*)d_in[18];
  const float* W3l = (const float*)d_in[19]; const float* b3l = (const float*)d_in[20];
  const float* W3r = (const float*)d_in[21]; const float* b3r = (const float*)d_in[22];
  const float* a3  = (const float*)d_in[23]; const float* bo3 = (const float*)d_in[24];
  const float* g3  = (const float*)d_in[25]; const float* be3 = (const float*)d_in[26];
  const float* linW = (const float*)d_in[27]; const float* linb = (const float*)d_in[28];

  char* ws = (char*)d_ws;
  float* xl      = (float*)ws;          ws += (size_t)Nn * 256 * 4;
  float* xr      = (float*)ws;          ws += (size_t)Nn * 256 * 4;
  float* h       = (float*)ws;          ws += (size_t)Nn * 256 * 4;
  unsigned short* Xb = (unsigned short*)ws; ws += (size_t)Nn * 256 * 2;
  unsigned short* Wtl = (unsigned short*)ws; ws += 256 * 256 * 2;
  unsigned short* Wtr = (unsigned short*)ws; ws += 256 * 256 * 2;
  int*   deg    = (int*)ws;    ws += (size_t)Nn * 4;
  int*   cursor = (int*)ws;    ws += (size_t)Nn * 4;
  int*   rowptr = (int*)ws;    ws += (size_t)(Nn + 1) * 4;
  int*   csr_src= (int*)ws;    ws += (size_t)Ee * 4;

  const int eblk = (Ee + 255) / 256;

  // ---------------- CSR build (by dst) ----------------
  hipMemsetAsync(deg, 0, (size_t)Nn * 4, stream);
  hipMemsetAsync(cursor, 0, (size_t)Nn * 4, stream);
  hist_deg<<<eblk, 256, 0, stream>>>(dst, deg, Ee);
  scan_deg<<<1, 1024, 0, stream>>>(deg, rowptr, Nn);
  fill_csr<<<eblk, 256, 0, stream>>>(src, dst, rowptr, cursor, csr_src, Ee);

  // ---------------- layer 1: 128 -> 4x64 ----------------
  cvt_bf16<<<(Nn * 128 / 4 + 255) / 256, 256, 0, stream>>>(x, Xb, Nn * 128 / 4);
  wt_cvt<<<(256 * 128 / 8 + 255) / 256, 256, 0, stream>>>(W1l, Wtl, 128, 256);
  wt_cvt<<<(256 * 128 / 8 + 255) / 256, 256, 0, stream>>>(W1r, Wtr, 128, 256);
  gemm_mfma<128, 2><<<dim3((Nn + 127) / 128, 4), 256, 0, stream>>>(Xb, Wtl, b1l, xl, Nn, 256);
  gemm_mfma<128, 2><<<dim3((Nn + 127) / 128, 4), 256, 0, stream>>>(Xb, Wtr, b1r, xr, Nn, 256);
  gat_fused<4><<<Nn, 256, 0, stream>>>(xl, xr, a1, rowptr, csr_src, bo1, g1, be1, h, Nn);

  // ---------------- layer 2: 256 -> 4x64 ----------------
  cvt_bf16<<<(Nn * 256 / 4 + 255) / 256, 256, 0, stream>>>(h, Xb, Nn * 256 / 4);
  wt_cvt<<<(256 * 256 / 8 + 255) / 256, 256, 0, stream>>>(W2l, Wtl, 256, 256);
  wt_cvt<<<(256 * 256 / 8 + 255) / 256, 256, 0, stream>>>(W2r, Wtr, 256, 256);
  gemm_mfma<256, 2><<<dim3((Nn + 127) / 128, 4), 256, 0, stream>>>(Xb, Wtl, b2l, xl, Nn, 256);
  gemm_mfma<256, 2><<<dim3((Nn + 127) / 128, 4), 256, 0, stream>>>(Xb, Wtr, b2r, xr, Nn, 256);
  gat_fused<4><<<Nn, 256, 0, stream>>>(xl, xr, a2, rowptr, csr_src, bo2, g2, be2, h, Nn);

  // ---------------- layer 3: 256 -> 1x64 ----------------
  cvt_bf16<<<(Nn * 256 / 4 + 255) / 256, 256, 0, stream>>>(h, Xb, Nn * 256 / 4);
  wt_cvt<<<(64 * 256 / 8 + 255) / 256, 256, 0, stream>>>(W3l, Wtl, 256, 64);
  wt_cvt<<<(64 * 256 / 8 + 255) / 256, 256, 0, stream>>>(W3r, Wtr, 256, 64);
  gemm_mfma<256, 1><<<dim3((Nn + 63) / 64, 1), 256, 0, stream>>>(Xb, Wtl, b3l, xl, Nn, 64);
  gemm_mfma<256, 1><<<dim3((Nn + 63) / 64, 1), 256, 0, stream>>>(Xb, Wtr, b3r, xr, Nn, 64);
  gat_fused<1><<<(Nn + 3) / 4, 256, 0, stream>>>(xl, xr, a3, rowptr, csr_src, bo3, g3, be3, h, Nn);

  // ---------------- final linear 64 -> 64 (f32, protects output accuracy) ----------------
  gemm_rows<64, 64, 16><<<(Nn + 15) / 16, 256, 0, stream>>>(h, linW, linb, (float*)d_out, Nn);
}

// Round 5
// 715.163 us; speedup vs baseline: 4.9586x; 1.1175x over previous
//
#include <hip/hip_runtime.h>
#include <math.h>

#define LRELU_SLOPE 0.2f

typedef __attribute__((ext_vector_type(8))) short bf16x8;
typedef __attribute__((ext_vector_type(4))) float f32x4;

// ---------------- f32 -> bf16 (RNE) ----------------
__device__ __forceinline__ unsigned short f2bf(float f) {
  unsigned u = __float_as_uint(f);
  return (unsigned short)((u + 0x7FFFu + ((u >> 16) & 1u)) >> 16);
}

__global__ void cvt_bf16(const float* __restrict__ in, unsigned short* __restrict__ out, int n4) {
  int i = blockIdx.x * blockDim.x + threadIdx.x;
  if (i >= n4) return;
  float4 v = *(const float4*)(in + (size_t)i * 4);
  ushort4 o;
  o.x = f2bf(v.x); o.y = f2bf(v.y); o.z = f2bf(v.z); o.w = f2bf(v.w);
  *(ushort4*)(out + (size_t)i * 4) = o;
}

// W[K][N] f32 -> Wt[N][K] bf16
__global__ void wt_cvt(const float* __restrict__ W, unsigned short* __restrict__ Wt, int K, int N) {
  int i = blockIdx.x * blockDim.x + threadIdx.x;
  int k8s = K / 8;
  int n = i / k8s, k8 = i - n * k8s;
  if (n >= N) return;
  unsigned short tmp[8];
#pragma unroll
  for (int j = 0; j < 8; ++j) tmp[j] = f2bf(W[(size_t)(k8 * 8 + j) * N + n]);
  *(bf16x8*)(Wt + (size_t)n * K + k8 * 8) = *(bf16x8*)tmp;
}

// ---------------- MFMA GEMM pair: Y{0,1}[M][N] = Xb @ Wt{0,1}^T + bias ----------------
// 256 thr = 4 waves; wave w handles RT row-tiles of 16; blockIdx.y selects side+colblock.
template<int K, int RT>
__global__ __launch_bounds__(256) void gemm_mfma2(
    const unsigned short* __restrict__ Xb,
    const unsigned short* __restrict__ Wt0, const unsigned short* __restrict__ Wt1,
    const float* __restrict__ bias0, const float* __restrict__ bias1,
    float* __restrict__ Y0, float* __restrict__ Y1, int M, int N) {
  const int nblk = N >> 6;
  const int side = blockIdx.y / nblk;
  const int n0 = (blockIdx.y - side * nblk) * 64;
  const unsigned short* Wt = side ? Wt1 : Wt0;
  const float* bias = side ? bias1 : bias0;
  float* Y = side ? Y1 : Y0;

  const int t = threadIdx.x, w = t >> 6, l = t & 63;
  const int lr = l & 15, lk = l >> 4;
  const int rowBase = blockIdx.x * (RT * 64) + w * (RT * 16);

  f32x4 acc[RT][4];
#pragma unroll
  for (int rt = 0; rt < RT; ++rt)
#pragma unroll
    for (int nt = 0; nt < 4; ++nt) acc[rt][nt] = (f32x4){0.f, 0.f, 0.f, 0.f};

  const unsigned short* ap[RT];
#pragma unroll
  for (int rt = 0; rt < RT; ++rt) {
    int row = rowBase + rt * 16 + lr;
    if (row >= M) row = M - 1;
    ap[rt] = Xb + (size_t)row * K + lk * 8;
  }
  const unsigned short* bp = Wt + (size_t)(n0 + lr) * K + lk * 8;

#pragma unroll
  for (int k0 = 0; k0 < K; k0 += 32) {
    bf16x8 a[RT], b[4];
#pragma unroll
    for (int rt = 0; rt < RT; ++rt) a[rt] = *(const bf16x8*)(ap[rt] + k0);
#pragma unroll
    for (int nt = 0; nt < 4; ++nt) b[nt] = *(const bf16x8*)(bp + (size_t)nt * 16 * K + k0);
#pragma unroll
    for (int rt = 0; rt < RT; ++rt)
#pragma unroll
      for (int nt = 0; nt < 4; ++nt)
        acc[rt][nt] = __builtin_amdgcn_mfma_f32_16x16x32_bf16(a[rt], b[nt], acc[rt][nt], 0, 0, 0);
  }

#pragma unroll
  for (int nt = 0; nt < 4; ++nt) {
    float bv = bias[n0 + nt * 16 + lr];
#pragma unroll
    for (int rt = 0; rt < RT; ++rt) {
#pragma unroll
      for (int r = 0; r < 4; ++r) {
        int row = rowBase + rt * 16 + lk * 4 + r;
        if (row < M) Y[(size_t)row * N + n0 + nt * 16 + lr] = acc[rt][nt][r] + bv;
      }
    }
  }
}

// ---------------- f32 GEMM (final linear) ----------------
template<int K, int OUT, int ROWS>
__global__ __launch_bounds__(256) void gemm_rows(const float* __restrict__ X,
    const float* __restrict__ W, const float* __restrict__ bias,
    float* __restrict__ Y, int n) {
  __shared__ float xs[ROWS][K];
  constexpr int NG = 256 / OUT;
  constexpr int RPG = ROWS / NG;
  const int row0 = blockIdx.x * ROWS;
  const int tid = threadIdx.x;
  const int col = tid % OUT;
  const int rg  = tid / OUT;
  for (int i = tid; i < ROWS * K; i += 256) {
    int r = i / K, k = i - r * K;
    int row = row0 + r;
    xs[r][k] = (row < n) ? X[(size_t)row * K + k] : 0.f;
  }
  __syncthreads();
  float acc[RPG];
#pragma unroll
  for (int r = 0; r < RPG; ++r) acc[r] = 0.f;
  for (int k = 0; k < K; ++k) {
    float w = W[(size_t)k * OUT + col];
#pragma unroll
    for (int r = 0; r < RPG; ++r) acc[r] = fmaf(xs[rg * RPG + r][k], w, acc[r]);
  }
  float bv = bias[col];
#pragma unroll
  for (int r = 0; r < RPG; ++r) {
    int row = row0 + rg * RPG + r;
    if (row < n) Y[(size_t)row * OUT + col] = acc[r] + bv;
  }
}

// ---------------- CSR build ----------------
__global__ void hist_deg(const int* __restrict__ dst, int* __restrict__ deg, int Ee) {
  int e = blockIdx.x * blockDim.x + threadIdx.x;
  if (e < Ee) atomicAdd(&deg[dst[e]], 1);
}

__global__ void scan_deg(const int* __restrict__ deg, int* __restrict__ rowptr, int n) {
  __shared__ int tot[1024];
  const int t = threadIdx.x;
  const int chunk = (n + 1023) / 1024;
  const int lo = t * chunk;
  const int hi = min(n, lo + chunk);
  int s = 0;
  for (int i = lo; i < hi; ++i) s += deg[i];
  tot[t] = s;
  __syncthreads();
  for (int off = 1; off < 1024; off <<= 1) {
    int v = 0;
    if (t >= off) v = tot[t - off];
    __syncthreads();
    if (t >= off) tot[t] += v;
    __syncthreads();
  }
  int run = (t == 0) ? 0 : tot[t - 1];
  for (int i = lo; i < hi; ++i) { rowptr[i] = run; run += deg[i]; }
  if (t == 1023) rowptr[n] = tot[1023];
}

__global__ void fill_csr(const int* __restrict__ src, const int* __restrict__ dst,
                         const int* __restrict__ rowptr, int* __restrict__ cursor,
                         int* __restrict__ csr_src, int Ee) {
  int e = blockIdx.x * blockDim.x + threadIdx.x;
  if (e >= Ee) return;
  int d = dst[e];
  int p = atomicAdd(&cursor[d], 1);
  csr_src[rowptr[d] + p] = src[e];
}

// ---------------- fused GATv2 aggregation + bias + LayerNorm ----------------
// No-max softmax: s = sum exp(sc), o = sum exp(sc)*v  (scores are O(10), safe in f32).
// 4 edge-groups of 16 lanes run fully independent accumulation; combined once at end.
template<int Hh, bool BF16OUT>
__global__ __launch_bounds__(256) void gat_fused(
    const float* __restrict__ xl, const float* __restrict__ xr,
    const float* __restrict__ att,
    const int* __restrict__ rowptr, const int* __restrict__ csr_src,
    const float* __restrict__ bo, const float* __restrict__ gam,
    const float* __restrict__ bet, void* __restrict__ outp, int n) {
  const int OUT = Hh * 64;
  const int t = threadIdx.x;
  const int wv = t >> 6, lane = t & 63;
  const int grp = lane >> 4, c4 = lane & 15;
  __shared__ float red[4];
  int node, h;
  if (Hh == 4) { node = blockIdx.x; h = wv; }
  else         { node = blockIdx.x * 4 + wv; h = 0; }
  const bool active = node < n;
  const int cb = h * 64 + c4 * 4;

  float4 xr4 = {0.f, 0.f, 0.f, 0.f};
  float4 v   = {0.f, 0.f, 0.f, 0.f};
  int r0 = 0, r1 = 0;
  if (active) {
    xr4 = *(const float4*)(xr + (size_t)node * OUT + cb);
    r0 = rowptr[node];
    r1 = rowptr[node + 1];
  }
  const float4 at4 = *(const float4*)(att + cb);

  float s = 0.f;
  float4 o = {0.f, 0.f, 0.f, 0.f};

  {
    int i0 = r0 + grp;
    if (i0 < r1) {
      int sn = csr_src[i0];
      v = *(const float4*)(xl + (size_t)sn * OUT + cb);
    }
  }
  bool valid = (r0 + grp) < r1;

  for (int base = r0; base < r1; base += 4) {
    const float4 vc = v;
    const bool vld = valid;
    int inext = base + 4 + grp;
    valid = inext < r1;
    if (valid) {
      int sn = csr_src[inext];
      v = *(const float4*)(xl + (size_t)sn * OUT + cb);
    }
    float e0 = vc.x + xr4.x; e0 = fmaxf(e0, LRELU_SLOPE * e0);
    float e1 = vc.y + xr4.y; e1 = fmaxf(e1, LRELU_SLOPE * e1);
    float e2 = vc.z + xr4.z; e2 = fmaxf(e2, LRELU_SLOPE * e2);
    float e3 = vc.w + xr4.w; e3 = fmaxf(e3, LRELU_SLOPE * e3);
    float sc = fmaf(e3, at4.w, fmaf(e2, at4.z, fmaf(e1, at4.y, e0 * at4.x)));
    sc += __shfl_xor(sc, 1);
    sc += __shfl_xor(sc, 2);
    sc += __shfl_xor(sc, 4);
    sc += __shfl_xor(sc, 8);
    if (!vld) sc = -INFINITY;
    const float wown = __expf(sc);   // exp(-inf)=0 for invalid
    s += wown;
    o.x = fmaf(wown, vc.x, o.x);
    o.y = fmaf(wown, vc.y, o.y);
    o.z = fmaf(wown, vc.z, o.z);
    o.w = fmaf(wown, vc.w, o.w);
  }

  // combine the 4 edge-groups
  o.x += __shfl_xor(o.x, 16); o.y += __shfl_xor(o.y, 16);
  o.z += __shfl_xor(o.z, 16); o.w += __shfl_xor(o.w, 16);
  o.x += __shfl_xor(o.x, 32); o.y += __shfl_xor(o.y, 32);
  o.z += __shfl_xor(o.z, 32); o.w += __shfl_xor(o.w, 32);
  s += __shfl_xor(s, 16);
  s += __shfl_xor(s, 32);

  const float inv = 1.f / (s + 1e-16f);
  const float4 bo4 = *(const float4*)(bo + cb);
  const float v0 = fmaf(o.x, inv, bo4.x);
  const float v1 = fmaf(o.y, inv, bo4.y);
  const float v2 = fmaf(o.z, inv, bo4.z);
  const float v3 = fmaf(o.w, inv, bo4.w);

  // ---- LayerNorm over OUT channels ----
  float ls = v0 + v1 + v2 + v3;
#pragma unroll
  for (int off = 1; off < 64; off <<= 1) ls += __shfl_xor(ls, off);
  float mu;
  if (Hh == 4) {
    if (lane == 0) red[wv] = ls;
    __syncthreads();
    mu = (red[0] + red[1] + red[2] + red[3]) * (0.25f / 256.f);
  } else {
    mu = ls * (0.25f / 64.f);
  }
  const float d0 = v0 - mu, d1 = v1 - mu, d2 = v2 - mu, d3 = v3 - mu;
  float q = d0 * d0 + d1 * d1 + d2 * d2 + d3 * d3;
#pragma unroll
  for (int off = 1; off < 64; off <<= 1) q += __shfl_xor(q, off);
  float var;
  if (Hh == 4) {
    __syncthreads();
    if (lane == 0) red[wv] = q;
    __syncthreads();
    var = (red[0] + red[1] + red[2] + red[3]) * (0.25f / 256.f);
  } else {
    var = q * (0.25f / 64.f);
  }
  const float rs = rsqrtf(var + 1e-5f);

  if (active && grp == 0) {
    const float4 g4 = *(const float4*)(gam + cb);
    const float4 b4 = *(const float4*)(bet + cb);
    float r0f = fmaf(d0 * rs, g4.x, b4.x);
    float r1f = fmaf(d1 * rs, g4.y, b4.y);
    float r2f = fmaf(d2 * rs, g4.z, b4.z);
    float r3f = fmaf(d3 * rs, g4.w, b4.w);
    if (BF16OUT) {
      ushort4 res;
      res.x = f2bf(r0f); res.y = f2bf(r1f); res.z = f2bf(r2f); res.w = f2bf(r3f);
      *(ushort4*)((unsigned short*)outp + (size_t)node * OUT + cb) = res;
    } else {
      float4 res = {r0f, r1f, r2f, r3f};
      *(float4*)((float*)outp + (size_t)node * OUT + cb) = res;
    }
  }
}

extern "C" void kernel_launch(void* const* d_in, const int* in_sizes, int n_in,
                              void* d_out, int out_size, void* d_ws, size_t ws_size,
                              hipStream_t stream) {
  const float* x    = (const float*)d_in[0];
  const int*   eidx = (const int*)d_in[1];
  const int Nn = in_sizes[0] / 128;
  const int Ee = in_sizes[1] / 2;
  const int* src = eidx;
  const int* dst = eidx + Ee;

  const float* W1l = (const float*)d_in[3];  const float* b1l = (const float*)d_in[4];
  const float* W1r = (const float*)d_in[5];  const float* b1r = (const float*)d_in[6];
  const float* a1  = (const float*)d_in[7];  const float* bo1 = (const float*)d_in[8];
  const float* g1  = (const float*)d_in[9];  const float* be1 = (const float*)d_in[10];
  const float* W2l = (const float*)d_in[11]; const float* b2l = (const float*)d_in[12];
  const float* W2r = (const float*)d_in[13]; const float* b2r = (const float*)d_in[14];
  const float* a2  = (const float*)d_in[15]; const float* bo2 = (const float*)d_in[16];
  const float* g2  = (const float*)d_in[17]; const float* be2 = (const float*)d_in[18];
  const float* W3l = (const float*)d_in[19]; const float* b3l = (const float*)d_in[20];
  const float* W3r = (const float*)d_in[21]; const float* b3r = (const float*)d_in[22];
  const float* a3  = (const float*)d_in[23]; const float* bo3 = (const float*)d_in[24];
  const float* g3  = (const float*)d_in[25]; const float* be3 = (const float*)d_in[26];
  const float* linW = (const float*)d_in[27]; const float* linb = (const float*)d_in[28];

  char* ws = (char*)d_ws;
  float* xl      = (float*)ws;          ws += (size_t)Nn * 256 * 4;
  float* xr      = (float*)ws;          ws += (size_t)Nn * 256 * 4;
  float* h       = (float*)ws;          ws += (size_t)Nn * 256 * 4;
  unsigned short* Xb = (unsigned short*)ws; ws += (size_t)Nn * 256 * 2;
  unsigned short* Wtl = (unsigned short*)ws; ws += 256 * 256 * 2;
  unsigned short* Wtr = (unsigned short*)ws; ws += 256 * 256 * 2;
  int*   deg    = (int*)ws;    ws += (size_t)Nn * 4;
  int*   cursor = (int*)ws;    ws += (size_t)Nn * 4;
  int*   rowptr = (int*)ws;    ws += (size_t)(Nn + 1) * 4;
  int*   csr_src= (int*)ws;    ws += (size_t)Ee * 4;

  const int eblk = (Ee + 255) / 256;

  // ---------------- CSR build (by dst) ----------------
  hipMemsetAsync(deg, 0, (size_t)Nn * 4, stream);
  hipMemsetAsync(cursor, 0, (size_t)Nn * 4, stream);
  hist_deg<<<eblk, 256, 0, stream>>>(dst, deg, Ee);
  scan_deg<<<1, 1024, 0, stream>>>(deg, rowptr, Nn);
  fill_csr<<<eblk, 256, 0, stream>>>(src, dst, rowptr, cursor, csr_src, Ee);

  // ---------------- layer 1: 128 -> 4x64 ----------------
  cvt_bf16<<<(Nn * 128 / 4 + 255) / 256, 256, 0, stream>>>(x, Xb, Nn * 128 / 4);
  wt_cvt<<<(256 * 128 / 8 + 255) / 256, 256, 0, stream>>>(W1l, Wtl, 128, 256);
  wt_cvt<<<(256 * 128 / 8 + 255) / 256, 256, 0, stream>>>(W1r, Wtr, 128, 256);
  gemm_mfma2<128, 4><<<dim3((Nn + 255) / 256, 8), 256, 0, stream>>>(
      Xb, Wtl, Wtr, b1l, b1r, xl, xr, Nn, 256);
  gat_fused<4, true><<<Nn, 256, 0, stream>>>(xl, xr, a1, rowptr, csr_src, bo1, g1, be1, Xb, Nn);

  // ---------------- layer 2: 256 -> 4x64 ----------------
  wt_cvt<<<(256 * 256 / 8 + 255) / 256, 256, 0, stream>>>(W2l, Wtl, 256, 256);
  wt_cvt<<<(256 * 256 / 8 + 255) / 256, 256, 0, stream>>>(W2r, Wtr, 256, 256);
  gemm_mfma2<256, 4><<<dim3((Nn + 255) / 256, 8), 256, 0, stream>>>(
      Xb, Wtl, Wtr, b2l, b2r, xl, xr, Nn, 256);
  gat_fused<4, true><<<Nn, 256, 0, stream>>>(xl, xr, a2, rowptr, csr_src, bo2, g2, be2, Xb, Nn);

  // ---------------- layer 3: 256 -> 1x64 ----------------
  wt_cvt<<<(64 * 256 / 8 + 255) / 256, 256, 0, stream>>>(W3l, Wtl, 256, 64);
  wt_cvt<<<(64 * 256 / 8 + 255) / 256, 256, 0, stream>>>(W3r, Wtr, 256, 64);
  gemm_mfma2<256, 1><<<dim3((Nn + 63) / 64, 2), 256, 0, stream>>>(
      Xb, Wtl, Wtr, b3l, b3r, xl, xr, Nn, 64);
  gat_fused<1, false><<<(Nn + 3) / 4, 256, 0, stream>>>(xl, xr, a3, rowptr, csr_src, bo3, g3, be3, h, Nn);

  // ---------------- final linear 64 -> 64 (f32) ----------------
  gemm_rows<64, 64, 16><<<(Nn + 15) / 16, 256, 0, stream>>>(h, linW, linb, (float*)d_out, Nn);
}

// Round 6
// 661.779 us; speedup vs baseline: 5.3586x; 1.0807x over previous
//
#include <hip/hip_runtime.h>
#include <math.h>

#define LRELU_SLOPE 0.2f

typedef __attribute__((ext_vector_type(8))) short bf16x8;
typedef __attribute__((ext_vector_type(4))) float f32x4;

// ---------------- f32 <-> bf16 helpers ----------------
__device__ __forceinline__ unsigned short f2bf(float f) {
  unsigned u = __float_as_uint(f);
  return (unsigned short)((u + 0x7FFFu + ((u >> 16) & 1u)) >> 16);
}
__device__ __forceinline__ float bf2f(short b) {
  return __uint_as_float(((unsigned)(unsigned short)b) << 16);
}

__global__ void cvt_bf16(const float* __restrict__ in, unsigned short* __restrict__ out, int n4) {
  int i = blockIdx.x * blockDim.x + threadIdx.x;
  if (i >= n4) return;
  float4 v = *(const float4*)(in + (size_t)i * 4);
  ushort4 o;
  o.x = f2bf(v.x); o.y = f2bf(v.y); o.z = f2bf(v.z); o.w = f2bf(v.w);
  *(ushort4*)(out + (size_t)i * 4) = o;
}

// W[K][N] f32 -> Wt[N][K] bf16
__global__ void wt_cvt(const float* __restrict__ W, unsigned short* __restrict__ Wt, int K, int N) {
  int i = blockIdx.x * blockDim.x + threadIdx.x;
  int k8s = K / 8;
  int n = i / k8s, k8 = i - n * k8s;
  if (n >= N) return;
  unsigned short tmp[8];
#pragma unroll
  for (int j = 0; j < 8; ++j) tmp[j] = f2bf(W[(size_t)(k8 * 8 + j) * N + n]);
  *(bf16x8*)(Wt + (size_t)n * K + k8 * 8) = *(bf16x8*)tmp;
}

// ---------------- MFMA GEMM pair: Y{0,1}[M][N](bf16) = Xb @ Wt{0,1}^T + bias ----------------
template<int K, int RT>
__global__ __launch_bounds__(256) void gemm_mfma2(
    const unsigned short* __restrict__ Xb,
    const unsigned short* __restrict__ Wt0, const unsigned short* __restrict__ Wt1,
    const float* __restrict__ bias0, const float* __restrict__ bias1,
    unsigned short* __restrict__ Y0, unsigned short* __restrict__ Y1, int M, int N) {
  const int nblk = N >> 6;
  const int side = blockIdx.y / nblk;
  const int n0 = (blockIdx.y - side * nblk) * 64;
  const unsigned short* Wt = side ? Wt1 : Wt0;
  const float* bias = side ? bias1 : bias0;
  unsigned short* Y = side ? Y1 : Y0;

  const int t = threadIdx.x, w = t >> 6, l = t & 63;
  const int lr = l & 15, lk = l >> 4;
  const int rowBase = blockIdx.x * (RT * 64) + w * (RT * 16);

  f32x4 acc[RT][4];
#pragma unroll
  for (int rt = 0; rt < RT; ++rt)
#pragma unroll
    for (int nt = 0; nt < 4; ++nt) acc[rt][nt] = (f32x4){0.f, 0.f, 0.f, 0.f};

  const unsigned short* ap[RT];
#pragma unroll
  for (int rt = 0; rt < RT; ++rt) {
    int row = rowBase + rt * 16 + lr;
    if (row >= M) row = M - 1;
    ap[rt] = Xb + (size_t)row * K + lk * 8;
  }
  const unsigned short* bp = Wt + (size_t)(n0 + lr) * K + lk * 8;

#pragma unroll
  for (int k0 = 0; k0 < K; k0 += 32) {
    bf16x8 a[RT], b[4];
#pragma unroll
    for (int rt = 0; rt < RT; ++rt) a[rt] = *(const bf16x8*)(ap[rt] + k0);
#pragma unroll
    for (int nt = 0; nt < 4; ++nt) b[nt] = *(const bf16x8*)(bp + (size_t)nt * 16 * K + k0);
#pragma unroll
    for (int rt = 0; rt < RT; ++rt)
#pragma unroll
      for (int nt = 0; nt < 4; ++nt)
        acc[rt][nt] = __builtin_amdgcn_mfma_f32_16x16x32_bf16(a[rt], b[nt], acc[rt][nt], 0, 0, 0);
  }

#pragma unroll
  for (int nt = 0; nt < 4; ++nt) {
    float bv = bias[n0 + nt * 16 + lr];
#pragma unroll
    for (int rt = 0; rt < RT; ++rt) {
#pragma unroll
      for (int r = 0; r < 4; ++r) {
        int row = rowBase + rt * 16 + lk * 4 + r;
        if (row < M) Y[(size_t)row * N + n0 + nt * 16 + lr] = f2bf(acc[rt][nt][r] + bv);
      }
    }
  }
}

// ---------------- f32 GEMM (final linear) ----------------
template<int K, int OUT, int ROWS>
__global__ __launch_bounds__(256) void gemm_rows(const float* __restrict__ X,
    const float* __restrict__ W, const float* __restrict__ bias,
    float* __restrict__ Y, int n) {
  __shared__ float xs[ROWS][K];
  constexpr int NG = 256 / OUT;
  constexpr int RPG = ROWS / NG;
  const int row0 = blockIdx.x * ROWS;
  const int tid = threadIdx.x;
  const int col = tid % OUT;
  const int rg  = tid / OUT;
  for (int i = tid; i < ROWS * K; i += 256) {
    int r = i / K, k = i - r * K;
    int row = row0 + r;
    xs[r][k] = (row < n) ? X[(size_t)row * K + k] : 0.f;
  }
  __syncthreads();
  float acc[RPG];
#pragma unroll
  for (int r = 0; r < RPG; ++r) acc[r] = 0.f;
  for (int k = 0; k < K; ++k) {
    float w = W[(size_t)k * OUT + col];
#pragma unroll
    for (int r = 0; r < RPG; ++r) acc[r] = fmaf(xs[rg * RPG + r][k], w, acc[r]);
  }
  float bv = bias[col];
#pragma unroll
  for (int r = 0; r < RPG; ++r) {
    int row = row0 + rg * RPG + r;
    if (row < n) Y[(size_t)row * OUT + col] = acc[r] + bv;
  }
}

// ---------------- CSR build ----------------
__global__ void hist_deg(const int* __restrict__ dst, int* __restrict__ deg, int Ee) {
  int e = blockIdx.x * blockDim.x + threadIdx.x;
  if (e < Ee) atomicAdd(&deg[dst[e]], 1);
}

__global__ void scan_deg(const int* __restrict__ deg, int* __restrict__ rowptr, int n) {
  __shared__ int tot[1024];
  const int t = threadIdx.x;
  const int chunk = (n + 1023) / 1024;
  const int lo = t * chunk;
  const int hi = min(n, lo + chunk);
  int s = 0;
  for (int i = lo; i < hi; ++i) s += deg[i];
  tot[t] = s;
  __syncthreads();
  for (int off = 1; off < 1024; off <<= 1) {
    int v = 0;
    if (t >= off) v = tot[t - off];
    __syncthreads();
    if (t >= off) tot[t] += v;
    __syncthreads();
  }
  int run = (t == 0) ? 0 : tot[t - 1];
  for (int i = lo; i < hi; ++i) { rowptr[i] = run; run += deg[i]; }
  if (t == 1023) rowptr[n] = tot[1023];
}

__global__ void fill_csr(const int* __restrict__ src, const int* __restrict__ dst,
                         const int* __restrict__ rowptr, int* __restrict__ cursor,
                         int* __restrict__ csr_src, int Ee) {
  int e = blockIdx.x * blockDim.x + threadIdx.x;
  if (e >= Ee) return;
  int d = dst[e];
  int p = atomicAdd(&cursor[d], 1);
  csr_src[rowptr[d] + p] = src[e];
}

// ---------------- fused GATv2 aggregation + bias + LayerNorm ----------------
// bf16 xl/xr. 8 edge-groups of 8 lanes; lane holds 8 channels (bf16x8 = 16B).
// No-max softmax (scores O(10), safe in f32). 8 edges per wave-iteration.
template<int Hh, bool BF16OUT>
__global__ __launch_bounds__(256) void gat_fused(
    const unsigned short* __restrict__ xlb, const unsigned short* __restrict__ xrb,
    const float* __restrict__ att,
    const int* __restrict__ rowptr, const int* __restrict__ csr_src,
    const float* __restrict__ bo, const float* __restrict__ gam,
    const float* __restrict__ bet, void* __restrict__ outp, int n) {
  const int OUT = Hh * 64;
  const int t = threadIdx.x;
  const int wv = t >> 6, lane = t & 63;
  const int grp = lane >> 3, c8 = lane & 7;
  __shared__ float red[4];
  int node, h;
  if (Hh == 4) { node = blockIdx.x; h = wv; }
  else         { node = blockIdx.x * 4 + wv; h = 0; }
  const bool active = node < n;
  const int cb = h * 64 + c8 * 8;

  float xrf[8];
  int r0 = 0, r1 = 0;
  if (active) {
    bf16x8 xv = *(const bf16x8*)(xrb + (size_t)node * OUT + cb);
#pragma unroll
    for (int i = 0; i < 8; ++i) xrf[i] = bf2f(xv[i]);
    r0 = rowptr[node];
    r1 = rowptr[node + 1];
  } else {
#pragma unroll
    for (int i = 0; i < 8; ++i) xrf[i] = 0.f;
  }
  float atf[8];
  {
    float4 a0 = *(const float4*)(att + cb);
    float4 a1 = *(const float4*)(att + cb + 4);
    atf[0] = a0.x; atf[1] = a0.y; atf[2] = a0.z; atf[3] = a0.w;
    atf[4] = a1.x; atf[5] = a1.y; atf[6] = a1.z; atf[7] = a1.w;
  }

  float s = 0.f;
  float o[8];
#pragma unroll
  for (int i = 0; i < 8; ++i) o[i] = 0.f;

  bf16x8 v = {};
  {
    int i0 = r0 + grp;
    if (i0 < r1) {
      int sn = csr_src[i0];
      v = *(const bf16x8*)(xlb + (size_t)sn * OUT + cb);
    }
  }
  bool valid = (r0 + grp) < r1;

  for (int base = r0; base < r1; base += 8) {
    const bf16x8 vc = v;
    const bool vld = valid;
    int inext = base + 8 + grp;
    valid = inext < r1;
    if (valid) {
      int sn = csr_src[inext];
      v = *(const bf16x8*)(xlb + (size_t)sn * OUT + cb);
    }
    float vf[8];
#pragma unroll
    for (int i = 0; i < 8; ++i) vf[i] = bf2f(vc[i]);
    float sc = 0.f;
#pragma unroll
    for (int i = 0; i < 8; ++i) {
      float e = vf[i] + xrf[i];
      e = fmaxf(e, LRELU_SLOPE * e);
      sc = fmaf(e, atf[i], sc);
    }
    sc += __shfl_xor(sc, 1);
    sc += __shfl_xor(sc, 2);
    sc += __shfl_xor(sc, 4);
    if (!vld) sc = -INFINITY;
    const float wown = __expf(sc);   // exp(-inf)=0 for invalid
    s += wown;
#pragma unroll
    for (int i = 0; i < 8; ++i) o[i] = fmaf(wown, vf[i], o[i]);
  }

  // combine the 8 edge-groups
#pragma unroll
  for (int off = 8; off < 64; off <<= 1) {
#pragma unroll
    for (int i = 0; i < 8; ++i) o[i] += __shfl_xor(o[i], off);
    s += __shfl_xor(s, off);
  }

  const float inv = 1.f / (s + 1e-16f);
  float val[8];
  {
    float4 b0 = *(const float4*)(bo + cb);
    float4 b1 = *(const float4*)(bo + cb + 4);
    val[0] = fmaf(o[0], inv, b0.x); val[1] = fmaf(o[1], inv, b0.y);
    val[2] = fmaf(o[2], inv, b0.z); val[3] = fmaf(o[3], inv, b0.w);
    val[4] = fmaf(o[4], inv, b1.x); val[5] = fmaf(o[5], inv, b1.y);
    val[6] = fmaf(o[6], inv, b1.z); val[7] = fmaf(o[7], inv, b1.w);
  }

  // ---- LayerNorm over OUT channels ----
  float ls = 0.f;
#pragma unroll
  for (int i = 0; i < 8; ++i) ls += val[i];
  ls += __shfl_xor(ls, 1);
  ls += __shfl_xor(ls, 2);
  ls += __shfl_xor(ls, 4);
  float mu;
  if (Hh == 4) {
    if (lane == 0) red[wv] = ls;
    __syncthreads();
    mu = (red[0] + red[1] + red[2] + red[3]) * (1.f / 256.f);
  } else {
    mu = ls * (1.f / 64.f);
  }
  float d[8], q = 0.f;
#pragma unroll
  for (int i = 0; i < 8; ++i) { d[i] = val[i] - mu; q = fmaf(d[i], d[i], q); }
  q += __shfl_xor(q, 1);
  q += __shfl_xor(q, 2);
  q += __shfl_xor(q, 4);
  float var;
  if (Hh == 4) {
    __syncthreads();
    if (lane == 0) red[wv] = q;
    __syncthreads();
    var = (red[0] + red[1] + red[2] + red[3]) * (1.f / 256.f);
  } else {
    var = q * (1.f / 64.f);
  }
  const float rs = rsqrtf(var + 1e-5f);

  if (active && grp == 0) {
    float4 g0 = *(const float4*)(gam + cb);
    float4 g1 = *(const float4*)(gam + cb + 4);
    float4 e0 = *(const float4*)(bet + cb);
    float4 e1 = *(const float4*)(bet + cb + 4);
    float rv[8];
    rv[0] = fmaf(d[0] * rs, g0.x, e0.x); rv[1] = fmaf(d[1] * rs, g0.y, e0.y);
    rv[2] = fmaf(d[2] * rs, g0.z, e0.z); rv[3] = fmaf(d[3] * rs, g0.w, e0.w);
    rv[4] = fmaf(d[4] * rs, g1.x, e1.x); rv[5] = fmaf(d[5] * rs, g1.y, e1.y);
    rv[6] = fmaf(d[6] * rs, g1.z, e1.z); rv[7] = fmaf(d[7] * rs, g1.w, e1.w);
    if (BF16OUT) {
      unsigned short rb[8];
#pragma unroll
      for (int i = 0; i < 8; ++i) rb[i] = f2bf(rv[i]);
      *(bf16x8*)((unsigned short*)outp + (size_t)node * OUT + cb) = *(bf16x8*)rb;
    } else {
      float* fo = (float*)outp + (size_t)node * OUT + cb;
      *(float4*)fo = (float4){rv[0], rv[1], rv[2], rv[3]};
      *(float4*)(fo + 4) = (float4){rv[4], rv[5], rv[6], rv[7]};
    }
  }
}

extern "C" void kernel_launch(void* const* d_in, const int* in_sizes, int n_in,
                              void* d_out, int out_size, void* d_ws, size_t ws_size,
                              hipStream_t stream) {
  const float* x    = (const float*)d_in[0];
  const int*   eidx = (const int*)d_in[1];
  const int Nn = in_sizes[0] / 128;
  const int Ee = in_sizes[1] / 2;
  const int* src = eidx;
  const int* dst = eidx + Ee;

  const float* W1l = (const float*)d_in[3];  const float* b1l = (const float*)d_in[4];
  const float* W1r = (const float*)d_in[5];  const float* b1r = (const float*)d_in[6];
  const float* a1  = (const float*)d_in[7];  const float* bo1 = (const float*)d_in[8];
  const float* g1  = (const float*)d_in[9];  const float* be1 = (const float*)d_in[10];
  const float* W2l = (const float*)d_in[11]; const float* b2l = (const float*)d_in[12];
  const float* W2r = (const float*)d_in[13]; const float* b2r = (const float*)d_in[14];
  const float* a2  = (const float*)d_in[15]; const float* bo2 = (const float*)d_in[16];
  const float* g2  = (const float*)d_in[17]; const float* be2 = (const float*)d_in[18];
  const float* W3l = (const float*)d_in[19]; const float* b3l = (const float*)d_in[20];
  const float* W3r = (const float*)d_in[21]; const float* b3r = (const float*)d_in[22];
  const float* a3  = (const float*)d_in[23]; const float* bo3 = (const float*)d_in[24];
  const float* g3  = (const float*)d_in[25]; const float* be3 = (const float*)d_in[26];
  const float* linW = (const float*)d_in[27]; const float* linb = (const float*)d_in[28];

  char* ws = (char*)d_ws;
  unsigned short* xl  = (unsigned short*)ws; ws += (size_t)Nn * 256 * 2;
  unsigned short* xr  = (unsigned short*)ws; ws += (size_t)Nn * 256 * 2;
  unsigned short* Xb  = (unsigned short*)ws; ws += (size_t)Nn * 256 * 2;
  float* h            = (float*)ws;          ws += (size_t)Nn * 64 * 4;
  unsigned short* Wtl = (unsigned short*)ws; ws += 256 * 256 * 2;
  unsigned short* Wtr = (unsigned short*)ws; ws += 256 * 256 * 2;
  int*   deg    = (int*)ws;    ws += (size_t)Nn * 4;
  int*   cursor = (int*)ws;    ws += (size_t)Nn * 4;
  int*   rowptr = (int*)ws;    ws += (size_t)(Nn + 1) * 4;
  int*   csr_src= (int*)ws;    ws += (size_t)Ee * 4;

  const int eblk = (Ee + 255) / 256;

  // ---------------- CSR build (by dst) ----------------
  hipMemsetAsync(deg, 0, (size_t)Nn * 4, stream);
  hipMemsetAsync(cursor, 0, (size_t)Nn * 4, stream);
  hist_deg<<<eblk, 256, 0, stream>>>(dst, deg, Ee);
  scan_deg<<<1, 1024, 0, stream>>>(deg, rowptr, Nn);
  fill_csr<<<eblk, 256, 0, stream>>>(src, dst, rowptr, cursor, csr_src, Ee);

  // ---------------- layer 1: 128 -> 4x64 ----------------
  cvt_bf16<<<(Nn * 128 / 4 + 255) / 256, 256, 0, stream>>>(x, Xb, Nn * 128 / 4);
  wt_cvt<<<(256 * 128 / 8 + 255) / 256, 256, 0, stream>>>(W1l, Wtl, 128, 256);
  wt_cvt<<<(256 * 128 / 8 + 255) / 256, 256, 0, stream>>>(W1r, Wtr, 128, 256);
  gemm_mfma2<128, 4><<<dim3((Nn + 255) / 256, 8), 256, 0, stream>>>(
      Xb, Wtl, Wtr, b1l, b1r, xl, xr, Nn, 256);
  gat_fused<4, true><<<Nn, 256, 0, stream>>>(xl, xr, a1, rowptr, csr_src, bo1, g1, be1, Xb, Nn);

  // ---------------- layer 2: 256 -> 4x64 ----------------
  wt_cvt<<<(256 * 256 / 8 + 255) / 256, 256, 0, stream>>>(W2l, Wtl, 256, 256);
  wt_cvt<<<(256 * 256 / 8 + 255) / 256, 256, 0, stream>>>(W2r, Wtr, 256, 256);
  gemm_mfma2<256, 4><<<dim3((Nn + 255) / 256, 8), 256, 0, stream>>>(
      Xb, Wtl, Wtr, b2l, b2r, xl, xr, Nn, 256);
  gat_fused<4, true><<<Nn, 256, 0, stream>>>(xl, xr, a2, rowptr, csr_src, bo2, g2, be2, Xb, Nn);

  // ---------------- layer 3: 256 -> 1x64 ----------------
  wt_cvt<<<(64 * 256 / 8 + 255) / 256, 256, 0, stream>>>(W3l, Wtl, 256, 64);
  wt_cvt<<<(64 * 256 / 8 + 255) / 256, 256, 0, stream>>>(W3r, Wtr, 256, 64);
  gemm_mfma2<256, 1><<<dim3((Nn + 63) / 64, 2), 256, 0, stream>>>(
      Xb, Wtl, Wtr, b3l, b3r, xl, xr, Nn, 64);
  gat_fused<1, false><<<(Nn + 3) / 4, 256, 0, stream>>>(xl, xr, a3, rowptr, csr_src, bo3, g3, be3, h, Nn);

  // ---------------- final linear 64 -> 64 (f32) ----------------
  gemm_rows<64, 64, 16><<<(Nn + 15) / 16, 256, 0, stream>>>(h, linW, linb, (float*)d_out, Nn);
}